// Round 13
// baseline (335.623 us; speedup 1.0000x reference)
//
#include <hip/hip_runtime.h>

#define NUMH 16
#define HD   64
#define SEQ  2048
#define NB   2
#define DIM  1024
#define MROWS (NB * SEQ)
#define QSCALE 0.180336880111f   // 0.125 * log2(e): folds softmax exp->exp2

typedef __attribute__((ext_vector_type(8))) short short8;
typedef __attribute__((ext_vector_type(4))) float f32x4;
typedef unsigned short u16;
typedef unsigned int u32;

__device__ inline u16 bf16_rn(float f) {
    unsigned u = __float_as_uint(f);
    return (u16)((u + 0x7FFFu + ((u >> 16) & 1u)) >> 16);
}
__device__ inline float bf16f(u16 h) {
    return __uint_as_float(((unsigned)h) << 16);
}

// Async global->LDS DMA, 16B per lane. LDS dest = wave-uniform base + lane*16.
#define GLD16(gp, lp)                                                        \
    __builtin_amdgcn_global_load_lds(                                        \
        (const __attribute__((address_space(1))) void*)(gp),                 \
        (__attribute__((address_space(3))) void*)(lp), 16, 0, 0)

// ---------------------------------------------------------------------------
// fp32 -> bf16 hi/lo split, elementwise ([M][K] kept)
// ---------------------------------------------------------------------------
__global__ void convert_split(const float* __restrict__ in,
                              u16* __restrict__ hi, u16* __restrict__ lo, int n4)
{
    for (int i = blockIdx.x * blockDim.x + threadIdx.x; i < n4;
         i += gridDim.x * blockDim.x) {
        const float4 v = ((const float4*)in)[i];
        ushort4 h, l;
        h.x = bf16_rn(v.x); l.x = bf16_rn(v.x - bf16f(h.x));
        h.y = bf16_rn(v.y); l.y = bf16_rn(v.y - bf16f(h.y));
        h.z = bf16_rn(v.z); l.z = bf16_rn(v.z - bf16f(h.z));
        h.w = bf16_rn(v.w); l.w = bf16_rn(v.w - bf16f(h.w));
        ((ushort4*)hi)[i] = h;
        ((ushort4*)lo)[i] = l;
    }
}

// ---------------------------------------------------------------------------
// W [K][N] fp32 -> Wt_hi/Wt_lo [N][K] bf16 (transpose + split), * scale
// ---------------------------------------------------------------------------
__global__ __launch_bounds__(256)
void transpose_split(const float* __restrict__ W,
                     u16* __restrict__ th, u16* __restrict__ tl, float scale)
{
    __shared__ float Ls[32][33];
    const int tx = threadIdx.x & 31, ty = threadIdx.x >> 5;
    const int k0 = blockIdx.x * 32, n0 = blockIdx.y * 32;
#pragma unroll
    for (int i = 0; i < 4; ++i)
        Ls[ty + 8 * i][tx] = W[(size_t)(k0 + ty + 8 * i) * DIM + n0 + tx];
    __syncthreads();
#pragma unroll
    for (int i = 0; i < 4; ++i) {
        const float f = Ls[tx][ty + 8 * i] * scale;
        const u16 h = bf16_rn(f);
        const u16 l = bf16_rn(f - bf16f(h));
        th[(size_t)(n0 + ty + 8 * i) * DIM + k0 + tx] = h;
        tl[(size_t)(n0 + ty + 8 * i) * DIM + k0 + tx] = l;
    }
}

// ---------------------------------------------------------------------------
// bf16-split MFMA GEMM, double-buffered GLD16 (T3-minimum: issue-early /
// drain-late, ONE barrier per K-step). LDS 48 KB, 3 blocks/CU.
// ---------------------------------------------------------------------------
template<int EPI>
__global__ __launch_bounds__(256, 3)
void gemm_split(const u16* __restrict__ Ah, const u16* __restrict__ Al,
                const u16* __restrict__ Bh, const u16* __restrict__ Bl,
                const float* __restrict__ bias, float bscale,
                float* __restrict__ outF, u16* __restrict__ outH,
                u16* __restrict__ outL)
{
    __shared__ u16 AsH[2][128][32];
    __shared__ u16 AsL[2][128][32];
    __shared__ u16 BsH[2][64][32];
    __shared__ u16 BsL[2][64][32];

    const int tid  = threadIdx.x;
    const int m0   = blockIdx.x * 128;
    const int n0   = blockIdx.y * 64;
    const int wid  = tid >> 6;
    const int lane = tid & 63;
    const int wr   = wid >> 1;
    const int wc   = wid & 1;
    const int fr   = lane & 15;
    const int fg   = lane >> 4;
    const int K    = DIM;

    f32x4 acc[4][2];
#pragma unroll
    for (int i = 0; i < 4; ++i)
#pragma unroll
        for (int j = 0; j < 2; ++j) { f32x4 z = {0.f, 0.f, 0.f, 0.f}; acc[i][j] = z; }

    const int gr = (wid << 4) + (lane >> 2);   // tile row this lane fetches
    const int gc = (lane & 3) * 8;             // elem col within K-chunk

    auto STAGE = [&](int buf, int kt) {
        GLD16(&Ah[(size_t)(m0 + gr) * K + kt + gc],      &AsH[buf][(wid << 4)][0]);
        GLD16(&Ah[(size_t)(m0 + 64 + gr) * K + kt + gc], &AsH[buf][64 + (wid << 4)][0]);
        GLD16(&Al[(size_t)(m0 + gr) * K + kt + gc],      &AsL[buf][(wid << 4)][0]);
        GLD16(&Al[(size_t)(m0 + 64 + gr) * K + kt + gc], &AsL[buf][64 + (wid << 4)][0]);
        GLD16(&Bh[(size_t)(n0 + gr) * K + kt + gc],      &BsH[buf][(wid << 4)][0]);
        GLD16(&Bl[(size_t)(n0 + gr) * K + kt + gc],      &BsL[buf][(wid << 4)][0]);
    };

    STAGE(0, 0);
    __syncthreads();   // vmcnt(0) drained by compiler: tile 0 ready

    for (int kt = 0; kt < K; kt += 32) {
        const int cur = (kt >> 5) & 1;
        if (kt + 32 < K) STAGE(cur ^ 1, kt + 32);   // issue next loads FIRST

        short8 afh[4], afl[4], bfh[2], bfl[2];
#pragma unroll
        for (int i = 0; i < 4; ++i) {
            afh[i] = *(const short8*)&AsH[cur][wr * 64 + i * 16 + fr][fg * 8];
            afl[i] = *(const short8*)&AsL[cur][wr * 64 + i * 16 + fr][fg * 8];
        }
#pragma unroll
        for (int j = 0; j < 2; ++j) {
            bfh[j] = *(const short8*)&BsH[cur][wc * 32 + j * 16 + fr][fg * 8];
            bfl[j] = *(const short8*)&BsL[cur][wc * 32 + j * 16 + fr][fg * 8];
        }
#pragma unroll
        for (int i = 0; i < 4; ++i)
#pragma unroll
            for (int j = 0; j < 2; ++j) {
                acc[i][j] = __builtin_amdgcn_mfma_f32_16x16x32_bf16(afl[i], bfh[j], acc[i][j], 0, 0, 0);
                acc[i][j] = __builtin_amdgcn_mfma_f32_16x16x32_bf16(afh[i], bfl[j], acc[i][j], 0, 0, 0);
                acc[i][j] = __builtin_amdgcn_mfma_f32_16x16x32_bf16(afh[i], bfh[j], acc[i][j], 0, 0, 0);
            }

        __syncthreads();   // drain: next loads landed during MFMA; LDS reuse safe
    }

#pragma unroll
    for (int i = 0; i < 4; ++i)
#pragma unroll
        for (int j = 0; j < 2; ++j) {
            const int col = n0 + wc * 32 + j * 16 + fr;
            const float bv = bias[col] * bscale;
            if (EPI == 2) {
                const int row = m0 + wr * 64 + i * 16 + fg * 4;
                const int b  = row >> 11;
                const int s  = row & (SEQ - 1);
                const int hh = col >> 6;
                const int hd = col & (HD - 1);
                ushort4 pk;
                pk.x = bf16_rn(acc[i][j][0] + bv);
                pk.y = bf16_rn(acc[i][j][1] + bv);
                pk.z = bf16_rn(acc[i][j][2] + bv);
                pk.w = bf16_rn(acc[i][j][3] + bv);
                *(ushort4*)&outH[((size_t)(b * NUMH + hh) * HD + hd) * SEQ + s] = pk;
            } else {
#pragma unroll
                for (int r = 0; r < 4; ++r) {
                    const int row = m0 + wr * 64 + i * 16 + fg * 4 + r;
                    const float v = acc[i][j][r] + bv;
                    if (EPI == 0) {
                        outF[(size_t)row * DIM + col] = v;
                    } else {
                        const int b  = row >> 11;
                        const int s  = row & (SEQ - 1);
                        const int hh = col >> 6;
                        const int hd = col & (HD - 1);
                        const size_t idx = ((size_t)(b * NUMH + hh) * SEQ + s) * HD + hd;
                        const u16 hv = bf16_rn(v);
                        outH[idx] = hv;
                        outL[idx] = bf16_rn(v - bf16f(hv));
                    }
                }
            }
        }
}

// ---------------------------------------------------------------------------
// MFMA flash attention v5: block = 128 CONTIGUOUS q-rows [128p, 128p+128) of
// one bh. Warps 0-3 own 64-tile 2p, warps 4-7 own 2p+1 (qt_w = 2p+(w>>2)) ->
// idle warp-iters ~3% (vs ~33% in v4). LDS double-buffer, ONE barrier/tile.
// exp2 softmax (log2e folded into Q scale). XCD chunk + heavy-first.
// ---------------------------------------------------------------------------
__global__ __launch_bounds__(512, 4)
void attn_mfma5(const u16* __restrict__ Qh, const u16* __restrict__ Ql,
                const u16* __restrict__ Kh, const u16* __restrict__ Kl,
                const u16* __restrict__ Vt,
                u16* __restrict__ ctxH, u16* __restrict__ ctxL)
{
    __shared__ u16 KsH[2][64 * 64];
    __shared__ u16 KsL[2][64 * 64];
    __shared__ u16 Vs [2][64 * 64];

    const int tid  = threadIdx.x;
    const int w    = tid >> 6;               // 0..7
    const int lane = tid & 63;
    const int lc   = lane & 15;
    const int g    = lane >> 4;

    // 512 blocks: XCD = orig&7 gets 4 contiguous bh; p descending (heavy-first)
    const int orig = blockIdx.x;
    const int j    = orig >> 3;
    const int bh   = (orig & 7) * 4 + (j >> 4);
    const int p    = 15 - (j & 15);
    const int qt_w = 2 * p + (w >> 2);       // this warp's 64-row q-tile index
    const int wq   = w & 3;                  // 16-row slice within the 64-tile
    const int NT   = 2 * p + 2;              // staged k-tiles: 0..2p+1

    const int bb = bh >> 4, hq = bh & 15;
    const size_t kqBase = (size_t)bh * SEQ * HD;
    const size_t vBase  = (size_t)bh * HD * SEQ;

    // Q B-frags: lane holds Q[q = qt_w*64 + wq*16 + lc][d = s2*32 + g*8 + j]
    short8 qh[2], ql[2];
    {
        const size_t ra = kqBase + (size_t)(qt_w * 64 + wq * 16 + lc) * HD;
        qh[0] = *(const short8*)&Qh[ra + g * 8];  qh[1] = *(const short8*)&Qh[ra + 32 + g * 8];
        ql[0] = *(const short8*)&Ql[ra + g * 8];  ql[1] = *(const short8*)&Ql[ra + 32 + g * 8];
    }

    f32x4 o[4];
#pragma unroll
    for (int f4 = 0; f4 < 4; ++f4) { f32x4 z = {0.f, 0.f, 0.f, 0.f}; o[f4] = z; }
    float mrun = -1e30f, lrun = 0.f;

    // staging: 512 threads, one 16B chunk per buffer; swizzle ^((row&7)<<3)
    const int srow = tid >> 3;
    const int scol = (tid & 7) * 8;
    const int so   = srow * 64 + (scol ^ ((srow & 7) << 3));
    const int rsw  = (lc & 7) << 3;          // read-side swizzle

    short8 pf0, pf1, pf2;
    auto LOADT = [&](int kt) {
        const size_t kg = kqBase + (size_t)(kt * 64 + srow) * HD + scol;
        pf0 = *(const short8*)&Kh[kg];
        pf1 = *(const short8*)&Kl[kg];
        const size_t vg = vBase + (size_t)srow * SEQ + kt * 64 + scol;
        pf2 = *(const short8*)&Vt[vg];
    };

    // bpermute constants for P redistribution
    const int a0 = (((g & 1) * 2 + 0) * 16 + lc) * 4;
    const int a1 = (((g & 1) * 2 + 1) * 16 + lc) * 4;
    const bool hi = ((g >> 1) & 1) != 0;

    LOADT(0);
    *(short8*)&KsH[0][so] = pf0;
    *(short8*)&KsL[0][so] = pf1;
    *(short8*)&Vs [0][so] = pf2;
    __syncthreads();                         // buf0 ready

    for (int kt = 0; kt < NT; ++kt) {
        const int cur = kt & 1;
        if (kt + 1 < NT) LOADT(kt + 1);      // async loads overlap compute

        if (kt <= qt_w) {                    // warp-uniform duty (idles <=1 iter)
            const int k0 = kt * 64;

            // ---- scores: S^T[k][q] = mfma(K-frag, Q-frag) ----
            f32x4 sf[4];
#pragma unroll
            for (int f4 = 0; f4 < 4; ++f4) {
                f32x4 a = {0.f, 0.f, 0.f, 0.f};
#pragma unroll
                for (int s2 = 0; s2 < 2; ++s2) {
                    const int off = (f4 * 16 + lc) * 64 + ((s2 * 32 + g * 8) ^ rsw);
                    const short8 kh = *(const short8*)&KsH[cur][off];
                    const short8 kl = *(const short8*)&KsL[cur][off];
                    a = __builtin_amdgcn_mfma_f32_16x16x32_bf16(kh, ql[s2], a, 0, 0, 0);
                    a = __builtin_amdgcn_mfma_f32_16x16x32_bf16(kl, qh[s2], a, 0, 0, 0);
                    a = __builtin_amdgcn_mfma_f32_16x16x32_bf16(kh, qh[s2], a, 0, 0, 0);
                }
                sf[f4] = a;
            }

            // ---- mask + row-max + online-softmax (exp2 domain) ----
            const bool diag = (kt == qt_w);
            const int  qg   = qt_w * 64 + wq * 16 + lc;
            float pm = -1e30f;
#pragma unroll
            for (int f4 = 0; f4 < 4; ++f4)
#pragma unroll
                for (int r = 0; r < 4; ++r) {
                    float sv = sf[f4][r];
                    if (diag && (k0 + f4 * 16 + g * 4 + r > qg)) sv = -1e30f;
                    sf[f4][r] = sv;
                    pm = fmaxf(pm, sv);
                }
            pm = fmaxf(pm, __shfl_xor(pm, 16));
            pm = fmaxf(pm, __shfl_xor(pm, 32));
            const float mn = fmaxf(mrun, pm);
            const float sc = exp2f(mrun - mn);
            mrun = mn; lrun *= sc;
#pragma unroll
            for (int f4 = 0; f4 < 4; ++f4) o[f4] *= sc;

            float ps = 0.f;
            u32 pk[4][2];
#pragma unroll
            for (int f4 = 0; f4 < 4; ++f4)
#pragma unroll
                for (int pr = 0; pr < 2; ++pr) {
                    const float p0 = exp2f(sf[f4][pr * 2 + 0] - mn);
                    const float p1 = exp2f(sf[f4][pr * 2 + 1] - mn);
                    ps += p0 + p1;
                    pk[f4][pr] = (u32)bf16_rn(p0) | ((u32)bf16_rn(p1) << 16);
                }
            ps += __shfl_xor(ps, 16);
            ps += __shfl_xor(ps, 32);
            lrun += ps;

            // ---- in-register P redistribute to PV B-frag layout ----
            u32 pb[2][4];
#pragma unroll
            for (int s2 = 0; s2 < 2; ++s2)
#pragma unroll
                for (int mm = 0; mm < 4; ++mm) {
                    const int addr = (mm < 2) ? a0 : a1;
                    const u32 t0 = (u32)__builtin_amdgcn_ds_bpermute(addr, (int)pk[s2 * 2 + 0][mm & 1]);
                    const u32 t1 = (u32)__builtin_amdgcn_ds_bpermute(addr, (int)pk[s2 * 2 + 1][mm & 1]);
                    pb[s2][mm] = hi ? t1 : t0;
                }

            // ---- PV: o^T[d][q] += mfma(V^T-frag, P^T-frag) ----
#pragma unroll
            for (int s2 = 0; s2 < 2; ++s2) {
                union { u32 u[4]; short8 s; } ua;
#pragma unroll
                for (int mm = 0; mm < 4; ++mm) ua.u[mm] = pb[s2][mm];
#pragma unroll
                for (int f4 = 0; f4 < 4; ++f4) {
                    const int off = (f4 * 16 + lc) * 64 + ((s2 * 32 + g * 8) ^ rsw);
                    const short8 vv = *(const short8*)&Vs[cur][off];
                    o[f4] = __builtin_amdgcn_mfma_f32_16x16x32_bf16(vv, ua.s, o[f4], 0, 0, 0);
                }
            }
        }

        if (kt + 1 < NT) {                   // write next tile (loads returned)
            *(short8*)&KsH[cur ^ 1][so] = pf0;
            *(short8*)&KsL[cur ^ 1][so] = pf1;
            *(short8*)&Vs [cur ^ 1][so] = pf2;
        }
        __syncthreads();                     // next buf ready / cur reads done
    }

    // ---- epilogue: o^T[d][q]/l -> ctx bf16 h/l [M][DIM] ----
    const float iv = 1.f / lrun;
    const size_t rowA = (size_t)bb * SEQ + qt_w * 64 + wq * 16 + lc;
#pragma unroll
    for (int f4 = 0; f4 < 4; ++f4) {
        const int colb = hq * HD + f4 * 16 + g * 4;
        ushort4 h4, l4;
#pragma unroll
        for (int r = 0; r < 4; ++r) {
            const float v = o[f4][r] * iv;
            const u16 hv = bf16_rn(v);
            ((u16*)&h4)[r] = hv;
            ((u16*)&l4)[r] = bf16_rn(v - bf16f(hv));
        }
        *(ushort4*)&ctxH[rowA * DIM + colb] = h4;
        *(ushort4*)&ctxL[rowA * DIM + colb] = l4;
    }
}

// ---------------------------------------------------------------------------
extern "C" void kernel_launch(void* const* d_in, const int* in_sizes, int n_in,
                              void* d_out, int out_size, void* d_ws, size_t ws_size,
                              hipStream_t stream)
{
    const float* x  = (const float*)d_in[0];
    const float* Wq = (const float*)d_in[1];
    const float* bq = (const float*)d_in[2];
    const float* Wk = (const float*)d_in[3];
    const float* bk = (const float*)d_in[4];
    const float* Wv = (const float*)d_in[5];
    const float* bv = (const float*)d_in[6];
    const float* Wo = (const float*)d_in[7];
    const float* bo = (const float*)d_in[8];

    char* base = (char*)d_ws;
    const size_t MB = 1024 * 1024;
    u16* Qh_ = (u16*)(base + 0 * MB);
    u16* Ql_ = (u16*)(base + 8 * MB);
    u16* Kh_ = (u16*)(base + 16 * MB);
    u16* Kl_ = (u16*)(base + 24 * MB);
    u16* Vt_ = (u16*)(base + 32 * MB);
    u16* xh  = (u16*)(base + 40 * MB);   // reused as ctxH
    u16* xl  = (u16*)(base + 48 * MB);   // reused as ctxL
    u16* Wth = (u16*)(base + 56 * MB);
    u16* Wtl = (u16*)(base + 58 * MB);

    dim3 blk(256);
    dim3 gg(MROWS / 128, DIM / 64);
    dim3 gt(DIM / 32, DIM / 32);

    hipLaunchKernelGGL(convert_split, dim3(2048), blk, 0, stream,
                       x, xh, xl, MROWS * DIM / 4);

    // Q projection carries 0.125*log2(e) (exp->exp2 fold)
    hipLaunchKernelGGL(transpose_split, gt, blk, 0, stream, Wq, Wth, Wtl, QSCALE);
    hipLaunchKernelGGL((gemm_split<1>), gg, blk, 0, stream,
                       xh, xl, Wth, Wtl, bq, QSCALE, nullptr, Qh_, Ql_);

    hipLaunchKernelGGL(transpose_split, gt, blk, 0, stream, Wk, Wth, Wtl, 1.0f);
    hipLaunchKernelGGL((gemm_split<1>), gg, blk, 0, stream,
                       xh, xl, Wth, Wtl, bk, 1.0f, nullptr, Kh_, Kl_);

    hipLaunchKernelGGL(transpose_split, gt, blk, 0, stream, Wv, Wth, Wtl, 1.0f);
    hipLaunchKernelGGL((gemm_split<2>), gg, blk, 0, stream,
                       xh, xl, Wth, Wtl, bv, 1.0f, nullptr, Vt_, nullptr);

    hipLaunchKernelGGL(attn_mfma5, dim3(NB * NUMH * 16), dim3(512), 0, stream,
                       Qh_, Ql_, Kh_, Kl_, Vt_, xh, xl);   // ctx -> xh/xl

    hipLaunchKernelGGL(transpose_split, gt, blk, 0, stream, Wo, Wth, Wtl, 1.0f);
    hipLaunchKernelGGL((gemm_split<0>), gg, blk, 0, stream,
                       xh, xl, Wth, Wtl, bo, 1.0f, (float*)d_out, nullptr, nullptr);
}